// Round 14
// baseline (208.223 us; speedup 1.0000x reference)
//
#include <hip/hip_runtime.h>
#include <stdint.h>

#define NA    100800
#define NIMG  8
#define TOPK  2048
#define NBLK1 99              // ceil(NA / 1024)
typedef unsigned long long u64;

// ---------------- K1: coalesced scan -> dense conf-bits + per-block LDS hist ----------------
__global__ __launch_bounds__(256) void k1_scan(const float* __restrict__ pred,
                                               unsigned* __restrict__ cand32,
                                               int* __restrict__ hist_blocks) {
    __shared__ int lhist[64];
    int t = threadIdx.x;
    int m = blockIdx.y;
    if (t < 64) lhist[t] = 0;
    __syncthreads();
    const float4* p4 = reinterpret_cast<const float4*>(pred + (size_t)m * NA * 16);
    int row0blk = blockIdx.x * 1024;
    for (int pass = 0; pass < 4; ++pass) {
        int row0 = row0blk + pass * 256;
        int i1 = row0 * 4 + 2 * t + 1;
        int i2 = i1 + 512;
        float4 A = make_float4(0.f, 0.f, 0.f, 0.f);
        float4 B = make_float4(0.f, 0.f, 0.f, 0.f);
        if ((i1 >> 2) < NA) A = p4[i1];
        if ((i2 >> 2) < NA) B = p4[i2];
        float aw = __shfl_xor(A.w, 1);          // x15 of row rA (valid on even lanes)
        float bw = __shfl_xor(B.w, 1);          // x15 of row rB
        if (!(t & 1)) {
            int rA = row0 + (t >> 1);
            int rB = rA + 128;
            {
                float obj = A.x, x15 = aw;
                if (rA < NA) {
                    float conf = __fmul_rn(x15, obj);   // exact ref op
                    unsigned cb = 0u;
                    if (obj > 0.5f && conf > 0.5f) {
                        cb = __float_as_uint(conf);
                        atomicAdd(&lhist[min(63, (int)((cb - 0x3F000000u) >> 17))], 1);
                    }
                    cand32[(size_t)m * NA + rA] = cb;
                }
            }
            {
                float obj = B.x, x15 = bw;
                if (rB < NA) {
                    float conf = __fmul_rn(x15, obj);
                    unsigned cb = 0u;
                    if (obj > 0.5f && conf > 0.5f) {
                        cb = __float_as_uint(conf);
                        atomicAdd(&lhist[min(63, (int)((cb - 0x3F000000u) >> 17))], 1);
                    }
                    cand32[(size_t)m * NA + rB] = cb;
                }
            }
        }
    }
    __syncthreads();
    if (t < 64) hist_blocks[((size_t)m * NBLK1 + blockIdx.x) * 64 + t] = lhist[t];
}

// ---------------- K2a: reduce per-block hists + cutoff via suffix-scan (1 wave/image) ----------------
__global__ void k2a_cutoff(const int* __restrict__ hist_blocks, int* __restrict__ cut,
                           int* __restrict__ pos) {
    int m = blockIdx.x;
    int lane = threadIdx.x;                     // 64 threads
    int h = 0;
    #pragma unroll 4
    for (int b = 0; b < NBLK1; ++b)             // coalesced: 64 consecutive ints per b
        h += hist_blocks[((size_t)m * NBLK1 + b) * 64 + lane];
    #pragma unroll
    for (int off = 1; off < 64; off <<= 1) {    // inclusive suffix sum
        int src = lane + off;
        int v = __shfl(h, src < 64 ? src : lane);
        h += (src < 64) ? v : 0;
    }
    int total  = __shfl(h, 0);
    int needed = min(total, TOPK);
    u64 bal = __ballot(h >= needed);
    int cutoff = 63 - __clzll(bal);             // highest bin with suffix >= needed
    if (lane == 0) { cut[m] = cutoff; pos[m] = 0; }
}

// ---------------- K2b: compact bin>=cutoff; ONE atomic per 1024-thread block ----------------
__global__ __launch_bounds__(1024) void k2b_compact(const unsigned* __restrict__ cand32,
                                                    const int* __restrict__ cut,
                                                    u64* __restrict__ comp,
                                                    int* __restrict__ pos) {
    __shared__ int wbase[16];
    __shared__ int sbase;
    int m = blockIdx.y;
    int i = blockIdx.x * 1024 + threadIdx.x;
    int lane = threadIdx.x & 63, wid = threadIdx.x >> 6;
    unsigned cb = (i < NA) ? cand32[(size_t)m * NA + i] : 0u;
    int c = cut[m];
    bool keep = false;
    if (cb) keep = min(63, (int)((cb - 0x3F000000u) >> 17)) >= c;
    u64 bal = __ballot(keep);
    int cnt = __popcll(bal);
    if (lane == 0) wbase[wid] = cnt;
    __syncthreads();
    if (threadIdx.x == 0) {
        int s = 0;
        #pragma unroll
        for (int w = 0; w < 16; ++w) { int v = wbase[w]; wbase[w] = s; s += v; }
        sbase = s ? atomicAdd(&pos[m], s) : 0;
    }
    __syncthreads();
    if (keep) {
        int p = sbase + wbase[wid] + (int)__popcll(bal & ((1ull << lane) - 1ull));
        if (p < 4096)
            comp[(size_t)m * 4096 + p] = ((u64)cb << 32) | (u64)(0xFFFFFFFFu - (unsigned)i);
    }
}

// ---------------- K2c: counting-rank (4096 fine bins) -> sel + staged boxes ----------------
__global__ __launch_bounds__(1024) void k2c_rank(const u64* __restrict__ comp,
                                                 const int* __restrict__ pos,
                                                 const float* __restrict__ pred,
                                                 u64* __restrict__ sel,
                                                 float4* __restrict__ boxes) {
    __shared__ int fcnt[4096];
    __shared__ int fstart[4096];
    __shared__ u64 outb[4096];
    __shared__ int wsum[16];
    int m = blockIdx.x, t = threadIdx.x;
    int M = min(pos[m], 4096);
    const u64* c = comp + (size_t)m * 4096;
    #pragma unroll
    for (int r = 0; r < 4; ++r) { fcnt[t + r * 1024] = 0; outb[t + r * 1024] = 0ull; }
    __syncthreads();
    // phase 1: load keys (strided, coalesced) + fine histogram
    u64 kk[4]; int rb[4];
    #pragma unroll
    for (int r = 0; r < 4; ++r) {
        int i = t + r * 1024;
        kk[r] = 0ull; rb[r] = -1;
        if (i < M) {
            kk[r] = c[i];
            rb[r] = 4095 - (int)(((unsigned)(kk[r] >> 32) - 0x3F000000u) >> 11);
            atomicAdd(&fcnt[rb[r]], 1);
        }
    }
    __syncthreads();
    // phase 2: exclusive prefix sum over 4096 bins (thread t owns bins 4t..4t+3)
    int c0 = fcnt[4 * t], c1 = fcnt[4 * t + 1], c2 = fcnt[4 * t + 2], c3 = fcnt[4 * t + 3];
    int s = c0 + c1 + c2 + c3;
    int lane = t & 63, w = t >> 6;
    int incl = s;
    #pragma unroll
    for (int off = 1; off < 64; off <<= 1) {
        int v = __shfl_up(incl, off);
        if (lane >= off) incl += v;
    }
    if (lane == 63) wsum[w] = incl;
    __syncthreads();
    if (w == 0) {
        int v = (lane < 16) ? wsum[lane] : 0;
        #pragma unroll
        for (int off = 1; off < 16; off <<= 1) {
            int u = __shfl_up(v, off);
            if (lane >= off) v += u;
        }
        if (lane < 16) wsum[lane] = v;     // inclusive wave sums
    }
    __syncthreads();
    int base = (w > 0 ? wsum[w - 1] : 0) + (incl - s);
    fstart[4 * t]     = base;
    fstart[4 * t + 1] = base + c0;
    fstart[4 * t + 2] = base + c0 + c1;
    fstart[4 * t + 3] = base + c0 + c1 + c2;
    __syncthreads();
    // phase 3: scatter (slot order within bin arbitrary; fixed in phase 4)
    #pragma unroll
    for (int r = 0; r < 4; ++r) {
        if (rb[r] >= 0) {
            int old = atomicSub(&fcnt[rb[r]], 1);
            int slot = fstart[rb[r]] + old - 1;
            outb[slot] = kk[r];
        }
    }
    __syncthreads();
    // phase 4: deterministic cleanup — insertion-sort each bin's range desc
    #pragma unroll
    for (int r = 0; r < 4; ++r) {
        int b = t + r * 1024;
        int st = fstart[b];
        int en = (b < 4095) ? fstart[b + 1] : M;
        for (int x = st + 1; x < en; ++x) {
            u64 key = outb[x];
            int y = x - 1;
            while (y >= st && outb[y] < key) { outb[y + 1] = outb[y]; --y; }
            outb[y + 1] = key;
        }
    }
    __syncthreads();
    // phase 5: emit sel + staged xyxy boxes for top-2048
    #pragma unroll
    for (int r = 0; r < 2; ++r) {
        int i = t + r * 1024;
        u64 key = outb[i];
        sel[(size_t)m * TOPK + i] = key;
        float4 b = make_float4(0.f, 0.f, 0.f, 0.f);
        if (key) {
            unsigned idx = 0xFFFFFFFFu - (unsigned)(key & 0xFFFFFFFFull);
            const float4* rv = reinterpret_cast<const float4*>(pred + ((size_t)m * NA + idx) * 16);
            float4 v = rv[0];                   // [xc, yc, w, h]
            float hw = __fmul_rn(v.z, 0.5f), hh = __fmul_rn(v.w, 0.5f);
            b.x = __fsub_rn(v.x, hw);
            b.y = __fsub_rn(v.y, hh);
            b.z = __fadd_rn(v.x, hw);
            b.w = __fadd_rn(v.y, hh);
        }
        boxes[(size_t)m * TOPK + i] = b;
    }
}

// ---------------- K4: 2048x2048 suppression bitmask, TRANSPOSED (iou > 0.45) ----------------
__global__ __launch_bounds__(1024) void k4_masks(const float4* __restrict__ boxes,
                                                 u64* __restrict__ maskT) {
    __shared__ float4 bx[TOPK];
    int m   = blockIdx.y;
    int grp = blockIdx.x;                       // 64 groups of 32 rows
    for (int i = threadIdx.x; i < TOPK; i += 1024)
        bx[i] = boxes[(size_t)m * TOPK + i];
    __syncthreads();

    int il = threadIdx.x & 31;
    int w  = threadIdx.x >> 5;
    int i  = grp * 32 + il;
    float4 b1 = bx[i];
    float a1 = __fmul_rn(__fsub_rn(b1.z, b1.x), __fsub_rn(b1.w, b1.y));
    u64 bits = 0ull;
    #pragma unroll 4
    for (int jj = 0; jj < 64; ++jj) {
        float4 b2 = bx[w * 64 + jj];
        float a2 = __fmul_rn(__fsub_rn(b2.z, b2.x), __fsub_rn(b2.w, b2.y));
        float iw = fmaxf(__fsub_rn(fminf(b1.z, b2.z), fmaxf(b1.x, b2.x)), 0.f);
        float ih = fmaxf(__fsub_rn(fminf(b1.w, b2.w), fmaxf(b1.y, b2.y)), 0.f);
        float inter = __fmul_rn(iw, ih);
        float uni   = __fsub_rn(__fadd_rn(a1, a2), inter);   // (a1+a2)-inter, ref order
        float iou   = __fdiv_rn(inter, uni);
        if (iou > 0.45f) bits |= (1ull << jj);
    }
    maskT[((size_t)m * 32 + w) * 2048 + i] = bits;
}

// ---------------- K5: greedy scan (R9 structure) + FUSED output write ----------------
__global__ __launch_bounds__(1024) void k5_nms(const u64* __restrict__ sel,
                                               const u64* __restrict__ maskT,
                                               const float* __restrict__ pred,
                                               float4* __restrict__ out) {
    __shared__ u64 remv[32];
    __shared__ u64 kbshare[2];
    __shared__ u64 kws[32];
    int m = blockIdx.x;
    int t = threadIdx.x;
    int lane = t & 63;
    int wv = t >> 6;                            // wave id 0..15
    const u64* mt = maskT + (size_t)m * 32 * 2048;
    if (t < 32) remv[t] = 0ull;
    u64 dval = 0ull, sval = 0ull, tval = 0ull;
    int cflag = 0;
    if (wv == 0) {
        dval = mt[(size_t)0 * 2048 + lane];
        sval = sel[(size_t)m * TOPK + lane];
        tval = mt[(size_t)0 * 2048 + 64 + lane];
    }
    __syncthreads();
    for (int blk = 0; blk < 32; ++blk) {
        if (wv == 0) {
            u64 dn = 0ull, sn = 0ull, tn = 0ull;
            if (blk < 31) {
                int r = (blk + 1) * 64 + lane;
                dn = mt[(size_t)(blk + 1) * 2048 + r];
                sn = sel[(size_t)m * TOPK + r];
                if (blk < 30) tn = mt[(size_t)(blk + 1) * 2048 + r + 64];
            }
            u64 ext = remv[blk];
            u64 validw = __ballot(sval != 0ull);
            int sup = (int)((ext >> lane) & 1ull) | cflag
                    | (int)(((~validw) >> lane) & 1ull);
            u64 kb = 0ull;
            u64 bal = __ballot(sup == 0);
            while (bal) {
                int j = __ffsll((long long)bal) - 1;
                kb |= (1ull << j);
                sup |= (int)((dval >> j) & 1ull);
                u64 low = (j < 63) ? ((2ull << j) - 1ull) : ~0ull;
                bal = __ballot(sup == 0) & ~low;
            }
            cflag = (blk < 31 && (tval & kb)) ? 1 : 0;
            if (lane == 0) {
                kbshare[blk & 1] = kb;
                kws[blk] = kb;
            }
            dval = dn; sval = sn; tval = tn;
        } else if (blk >= 1) {
            u64 kb = kbshare[(blk - 1) & 1];
            int w1 = blk + wv;
            int w2 = blk + 15 + wv;
            u64 v1 = (w1 < 32) ? mt[(size_t)(blk - 1) * 2048 + w1 * 64 + lane] : 0ull;
            u64 v2 = (w2 < 32) ? mt[(size_t)(blk - 1) * 2048 + w2 * 64 + lane] : 0ull;
            u64 c1 = __ballot((v1 & kb) != 0ull);
            u64 c2 = __ballot((v2 & kb) != 0ull);
            if (w1 < 32 && lane == 0) remv[w1] |= c1;
            if (w2 < 32 && lane == 0) remv[w2] |= c2;
        }
        __syncthreads();
    }
    // fused output write
    const u64* sl = sel + (size_t)m * TOPK;
    float4* om = out + (size_t)m * TOPK * 4;
    #pragma unroll
    for (int q = t; q < TOPK * 4; q += 1024) {
        int c4 = q & 3;
        int r  = q >> 2;
        float4 o = make_float4(0.f, 0.f, 0.f, 0.f);
        if ((kws[r >> 6] >> (r & 63)) & 1ull) {
            u64 key = sl[r];
            unsigned idx = 0xFFFFFFFFu - (unsigned)(key & 0xFFFFFFFFull);
            const float4* rv = reinterpret_cast<const float4*>(pred + ((size_t)m * NA + idx) * 16);
            float4 v = rv[c4];
            if (c4 == 0) {
                float hw = __fmul_rn(v.z, 0.5f), hh = __fmul_rn(v.w, 0.5f);
                o = make_float4(__fsub_rn(v.x, hw), __fsub_rn(v.y, hh),
                                __fadd_rn(v.x, hw), __fadd_rn(v.y, hh));
            } else if (c4 == 1) {
                o = make_float4(__uint_as_float((unsigned)(key >> 32)), v.y, v.z, v.w);
            } else if (c4 == 2) {
                o = v;
            } else {
                o = make_float4(v.x, v.y, v.z, 0.f);
            }
        }
        om[q] = o;
    }
}

// ================= PROBES (write to d_ws scratch only; diagnostic) =================

// P1: full k5 structure WITHOUT the serial scan loop (kb == 0 always).
__global__ __launch_bounds__(1024) void probe_struct(const u64* __restrict__ sel,
                                                     const u64* __restrict__ maskT,
                                                     u64* __restrict__ scr) {
    __shared__ u64 remv[32];
    __shared__ u64 kbshare[2];
    int m = blockIdx.x;
    int t = threadIdx.x;
    int lane = t & 63;
    int wv = t >> 6;
    const u64* mt = maskT + (size_t)m * 32 * 2048;
    if (t < 32) remv[t] = 0ull;
    if (t < 2) kbshare[t] = 0ull;
    u64 dval = 0ull, sval = 0ull, tval = 0ull;
    if (wv == 0) {
        dval = mt[(size_t)0 * 2048 + lane];
        sval = sel[(size_t)m * TOPK + lane];
        tval = mt[(size_t)0 * 2048 + 64 + lane];
    }
    __syncthreads();
    for (int blk = 0; blk < 32; ++blk) {
        if (wv == 0) {
            u64 dn = 0ull, sn = 0ull, tn = 0ull;
            if (blk < 31) {
                int r = (blk + 1) * 64 + lane;
                dn = mt[(size_t)(blk + 1) * 2048 + r];
                sn = sel[(size_t)m * TOPK + r];
                if (blk < 30) tn = mt[(size_t)(blk + 1) * 2048 + r + 64];
            }
            u64 ext = remv[blk];
            u64 validw = __ballot(sval != 0ull);
            u64 kb = 0ull;                       // NO scan loop
            asm volatile("" :: "v"(dval), "v"(tval), "v"(ext), "v"(validw)); // keep live
            if (lane == 0) {
                kbshare[blk & 1] = kb;
                scr[m * 32 + blk] = kb;
            }
            dval = dn; sval = sn; tval = tn;
        } else if (blk >= 1) {
            u64 kb = kbshare[(blk - 1) & 1];
            int w1 = blk + wv;
            int w2 = blk + 15 + wv;
            u64 v1 = (w1 < 32) ? mt[(size_t)(blk - 1) * 2048 + w1 * 64 + lane] : 0ull;
            u64 v2 = (w2 < 32) ? mt[(size_t)(blk - 1) * 2048 + w2 * 64 + lane] : 0ull;
            u64 c1 = __ballot((v1 & kb) != 0ull);
            u64 c2 = __ballot((v2 & kb) != 0ull);
            if (w1 < 32 && lane == 0) remv[w1] |= c1;
            if (w2 < 32 && lane == 0) remv[w2] |= c2;
        }
        __syncthreads();
    }
}

// P2: 1 wave, prefetched diag/sel loads + the serial scan loop (ext=0, within-block only).
__global__ __launch_bounds__(64) void probe_scan(const u64* __restrict__ sel,
                                                 const u64* __restrict__ maskT,
                                                 u64* __restrict__ scr) {
    int m = blockIdx.x;
    int lane = threadIdx.x;
    const u64* mt = maskT + (size_t)m * 32 * 2048;
    const u64* sl = sel + (size_t)m * TOPK;
    u64 dA = mt[(size_t)0 * 2048 + lane];
    u64 sA = sl[lane];
    for (int blk = 0; blk < 32; ++blk) {
        u64 dn = 0ull, sn = 0ull;
        if (blk < 31) {
            int r = (blk + 1) * 64 + lane;
            dn = mt[(size_t)(blk + 1) * 2048 + r];
            sn = sl[r];
        }
        u64 validw = __ballot(sA != 0ull);
        int sup = (int)(((~validw) >> lane) & 1ull);
        u64 kb = 0ull;
        u64 bal = __ballot(sup == 0);
        while (bal) {
            int j = __ffsll((long long)bal) - 1;
            kb |= (1ull << j);
            sup |= (int)((dA >> j) & 1ull);
            u64 low = (j < 63) ? ((2ull << j) - 1ull) : ~0ull;
            bal = __ballot(sup == 0) & ~low;
        }
        if (lane == 0) scr[256 + m * 32 + blk] = kb;
        dA = dn; sA = sn;
    }
}

// P3: P2 without the while-loop — its load/ballot baseline.
__global__ __launch_bounds__(64) void probe_loads(const u64* __restrict__ sel,
                                                  const u64* __restrict__ maskT,
                                                  u64* __restrict__ scr) {
    int m = blockIdx.x;
    int lane = threadIdx.x;
    const u64* mt = maskT + (size_t)m * 32 * 2048;
    const u64* sl = sel + (size_t)m * TOPK;
    u64 dA = mt[(size_t)0 * 2048 + lane];
    u64 sA = sl[lane];
    for (int blk = 0; blk < 32; ++blk) {
        u64 dn = 0ull, sn = 0ull;
        if (blk < 31) {
            int r = (blk + 1) * 64 + lane;
            dn = mt[(size_t)(blk + 1) * 2048 + r];
            sn = sl[r];
        }
        u64 validw = __ballot(sA != 0ull);
        asm volatile("" :: "v"(dA));            // keep diag load live
        if (lane == 0) scr[512 + m * 32 + blk] = validw;
        dA = dn; sA = sn;
    }
}

// ---------------- launch ----------------
extern "C" void kernel_launch(void* const* d_in, const int* in_sizes, int n_in,
                              void* d_out, int out_size, void* d_ws, size_t ws_size,
                              hipStream_t stream) {
    (void)in_sizes; (void)n_in; (void)out_size; (void)ws_size;
    const float* pred = (const float*)d_in[0];
    char* ws = (char*)d_ws;
    // layout (bytes):
    unsigned* cand32   = (unsigned*)(ws + 0);          // 8*100800*4 = 3,225,600
    u64*      comp     = (u64*)     (ws + 3225600);    // 8*4096*8   =   262,144
    u64*      sel      = (u64*)     (ws + 3487744);    // 8*2048*8   =   131,072
    float4*   boxes    = (float4*)  (ws + 3618816);    // 8*2048*16  =   262,144
    u64*      maskT    = (u64*)     (ws + 3880960);    // 8*32*2048*8= 4,194,304
    int*      histb    = (int*)     (ws + 8077312);    // 8*99*64*4  =   202,752
    int*      pos      = (int*)     (ws + 8280064);    // 32
    int*      cut      = (int*)     (ws + 8280096);    // 32
    u64*      scr      = (u64*)     (ws + 8280128);    // probe scratch (6 KB)
    float4*   out      = (float4*)d_out;

    hipLaunchKernelGGL(k1_scan,    dim3(NBLK1, NIMG),            dim3(256),  0, stream, pred, cand32, histb);
    hipLaunchKernelGGL(k2a_cutoff, dim3(NIMG),                   dim3(64),   0, stream, histb, cut, pos);
    hipLaunchKernelGGL(k2b_compact,dim3(NBLK1, NIMG),            dim3(1024), 0, stream, cand32, cut, comp, pos);
    hipLaunchKernelGGL(k2c_rank,   dim3(NIMG),                   dim3(1024), 0, stream, comp, pos, pred, sel, boxes);
    hipLaunchKernelGGL(k4_masks,   dim3(64, NIMG),               dim3(1024), 0, stream, boxes, maskT);
    hipLaunchKernelGGL(k5_nms,     dim3(NIMG),                   dim3(1024), 0, stream, sel, maskT, pred, out);
    // diagnostic probes (scratch-only writes)
    hipLaunchKernelGGL(probe_struct, dim3(NIMG), dim3(1024), 0, stream, sel, maskT, scr);
    hipLaunchKernelGGL(probe_scan,   dim3(NIMG), dim3(64),   0, stream, sel, maskT, scr);
    hipLaunchKernelGGL(probe_loads,  dim3(NIMG), dim3(64),   0, stream, sel, maskT, scr);
}

// Round 15
// 100.648 us; speedup vs baseline: 2.0688x; 2.0688x over previous
//
#include <hip/hip_runtime.h>
#include <stdint.h>

#define NA    100800
#define NIMG  8
#define TOPK  2048
#define NBLK1 99              // ceil(NA / 1024)
typedef unsigned long long u64;

// ---------------- K1: coalesced scan -> dense conf-bits + per-block LDS hist ----------------
__global__ __launch_bounds__(256) void k1_scan(const float* __restrict__ pred,
                                               unsigned* __restrict__ cand32,
                                               int* __restrict__ hist_blocks) {
    __shared__ int lhist[64];
    int t = threadIdx.x;
    int m = blockIdx.y;
    if (t < 64) lhist[t] = 0;
    __syncthreads();
    const float4* p4 = reinterpret_cast<const float4*>(pred + (size_t)m * NA * 16);
    int row0blk = blockIdx.x * 1024;
    for (int pass = 0; pass < 4; ++pass) {
        int row0 = row0blk + pass * 256;
        int i1 = row0 * 4 + 2 * t + 1;
        int i2 = i1 + 512;
        float4 A = make_float4(0.f, 0.f, 0.f, 0.f);
        float4 B = make_float4(0.f, 0.f, 0.f, 0.f);
        if ((i1 >> 2) < NA) A = p4[i1];
        if ((i2 >> 2) < NA) B = p4[i2];
        float aw = __shfl_xor(A.w, 1);          // x15 of row rA (valid on even lanes)
        float bw = __shfl_xor(B.w, 1);          // x15 of row rB
        if (!(t & 1)) {
            int rA = row0 + (t >> 1);
            int rB = rA + 128;
            {
                float obj = A.x, x15 = aw;
                if (rA < NA) {
                    float conf = __fmul_rn(x15, obj);   // exact ref op
                    unsigned cb = 0u;
                    if (obj > 0.5f && conf > 0.5f) {
                        cb = __float_as_uint(conf);
                        atomicAdd(&lhist[min(63, (int)((cb - 0x3F000000u) >> 17))], 1);
                    }
                    cand32[(size_t)m * NA + rA] = cb;
                }
            }
            {
                float obj = B.x, x15 = bw;
                if (rB < NA) {
                    float conf = __fmul_rn(x15, obj);
                    unsigned cb = 0u;
                    if (obj > 0.5f && conf > 0.5f) {
                        cb = __float_as_uint(conf);
                        atomicAdd(&lhist[min(63, (int)((cb - 0x3F000000u) >> 17))], 1);
                    }
                    cand32[(size_t)m * NA + rB] = cb;
                }
            }
        }
    }
    __syncthreads();
    if (t < 64) hist_blocks[((size_t)m * NBLK1 + blockIdx.x) * 64 + t] = lhist[t];
}

// ---------------- K2a: reduce per-block hists + cutoff via suffix-scan (1 wave/image) ----------------
__global__ void k2a_cutoff(const int* __restrict__ hist_blocks, int* __restrict__ cut,
                           int* __restrict__ pos) {
    int m = blockIdx.x;
    int lane = threadIdx.x;                     // 64 threads
    int h = 0;
    #pragma unroll 4
    for (int b = 0; b < NBLK1; ++b)             // coalesced: 64 consecutive ints per b
        h += hist_blocks[((size_t)m * NBLK1 + b) * 64 + lane];
    #pragma unroll
    for (int off = 1; off < 64; off <<= 1) {    // inclusive suffix sum
        int src = lane + off;
        int v = __shfl(h, src < 64 ? src : lane);
        h += (src < 64) ? v : 0;
    }
    int total  = __shfl(h, 0);
    int needed = min(total, TOPK);
    u64 bal = __ballot(h >= needed);
    int cutoff = 63 - __clzll(bal);             // highest bin with suffix >= needed
    if (lane == 0) { cut[m] = cutoff; pos[m] = 0; }
}

// ---------------- K2b: compact bin>=cutoff; ONE atomic per 1024-thread block ----------------
__global__ __launch_bounds__(1024) void k2b_compact(const unsigned* __restrict__ cand32,
                                                    const int* __restrict__ cut,
                                                    u64* __restrict__ comp,
                                                    int* __restrict__ pos) {
    __shared__ int wbase[16];
    __shared__ int sbase;
    int m = blockIdx.y;
    int i = blockIdx.x * 1024 + threadIdx.x;
    int lane = threadIdx.x & 63, wid = threadIdx.x >> 6;
    unsigned cb = (i < NA) ? cand32[(size_t)m * NA + i] : 0u;
    int c = cut[m];
    bool keep = false;
    if (cb) keep = min(63, (int)((cb - 0x3F000000u) >> 17)) >= c;
    u64 bal = __ballot(keep);
    int cnt = __popcll(bal);
    if (lane == 0) wbase[wid] = cnt;
    __syncthreads();
    if (threadIdx.x == 0) {
        int s = 0;
        #pragma unroll
        for (int w = 0; w < 16; ++w) { int v = wbase[w]; wbase[w] = s; s += v; }
        sbase = s ? atomicAdd(&pos[m], s) : 0;
    }
    __syncthreads();
    if (keep) {
        int p = sbase + wbase[wid] + (int)__popcll(bal & ((1ull << lane) - 1ull));
        if (p < 4096)
            comp[(size_t)m * 4096 + p] = ((u64)cb << 32) | (u64)(0xFFFFFFFFu - (unsigned)i);
    }
}

// ---------------- K2c: counting-rank (4096 fine bins) -> sel + staged boxes ----------------
__global__ __launch_bounds__(1024) void k2c_rank(const u64* __restrict__ comp,
                                                 const int* __restrict__ pos,
                                                 const float* __restrict__ pred,
                                                 u64* __restrict__ sel,
                                                 float4* __restrict__ boxes) {
    __shared__ int fcnt[4096];
    __shared__ int fstart[4096];
    __shared__ u64 outb[4096];
    __shared__ int wsum[16];
    int m = blockIdx.x, t = threadIdx.x;
    int M = min(pos[m], 4096);
    const u64* c = comp + (size_t)m * 4096;
    #pragma unroll
    for (int r = 0; r < 4; ++r) { fcnt[t + r * 1024] = 0; outb[t + r * 1024] = 0ull; }
    __syncthreads();
    // phase 1: load keys (strided, coalesced) + fine histogram
    u64 kk[4]; int rb[4];
    #pragma unroll
    for (int r = 0; r < 4; ++r) {
        int i = t + r * 1024;
        kk[r] = 0ull; rb[r] = -1;
        if (i < M) {
            kk[r] = c[i];
            rb[r] = 4095 - (int)(((unsigned)(kk[r] >> 32) - 0x3F000000u) >> 11);
            atomicAdd(&fcnt[rb[r]], 1);
        }
    }
    __syncthreads();
    // phase 2: exclusive prefix sum over 4096 bins (thread t owns bins 4t..4t+3)
    int c0 = fcnt[4 * t], c1 = fcnt[4 * t + 1], c2 = fcnt[4 * t + 2], c3 = fcnt[4 * t + 3];
    int s = c0 + c1 + c2 + c3;
    int lane = t & 63, w = t >> 6;
    int incl = s;
    #pragma unroll
    for (int off = 1; off < 64; off <<= 1) {
        int v = __shfl_up(incl, off);
        if (lane >= off) incl += v;
    }
    if (lane == 63) wsum[w] = incl;
    __syncthreads();
    if (w == 0) {
        int v = (lane < 16) ? wsum[lane] : 0;
        #pragma unroll
        for (int off = 1; off < 16; off <<= 1) {
            int u = __shfl_up(v, off);
            if (lane >= off) v += u;
        }
        if (lane < 16) wsum[lane] = v;     // inclusive wave sums
    }
    __syncthreads();
    int base = (w > 0 ? wsum[w - 1] : 0) + (incl - s);
    fstart[4 * t]     = base;
    fstart[4 * t + 1] = base + c0;
    fstart[4 * t + 2] = base + c0 + c1;
    fstart[4 * t + 3] = base + c0 + c1 + c2;
    __syncthreads();
    // phase 3: scatter (slot order within bin arbitrary; fixed in phase 4)
    #pragma unroll
    for (int r = 0; r < 4; ++r) {
        if (rb[r] >= 0) {
            int old = atomicSub(&fcnt[rb[r]], 1);
            int slot = fstart[rb[r]] + old - 1;
            outb[slot] = kk[r];
        }
    }
    __syncthreads();
    // phase 4: deterministic cleanup — insertion-sort each bin's range desc
    #pragma unroll
    for (int r = 0; r < 4; ++r) {
        int b = t + r * 1024;
        int st = fstart[b];
        int en = (b < 4095) ? fstart[b + 1] : M;
        for (int x = st + 1; x < en; ++x) {
            u64 key = outb[x];
            int y = x - 1;
            while (y >= st && outb[y] < key) { outb[y + 1] = outb[y]; --y; }
            outb[y + 1] = key;
        }
    }
    __syncthreads();
    // phase 5: emit sel + staged xyxy boxes for top-2048
    #pragma unroll
    for (int r = 0; r < 2; ++r) {
        int i = t + r * 1024;
        u64 key = outb[i];
        sel[(size_t)m * TOPK + i] = key;
        float4 b = make_float4(0.f, 0.f, 0.f, 0.f);
        if (key) {
            unsigned idx = 0xFFFFFFFFu - (unsigned)(key & 0xFFFFFFFFull);
            const float4* rv = reinterpret_cast<const float4*>(pred + ((size_t)m * NA + idx) * 16);
            float4 v = rv[0];                   // [xc, yc, w, h]
            float hw = __fmul_rn(v.z, 0.5f), hh = __fmul_rn(v.w, 0.5f);
            b.x = __fsub_rn(v.x, hw);
            b.y = __fsub_rn(v.y, hh);
            b.z = __fadd_rn(v.x, hw);
            b.w = __fadd_rn(v.y, hh);
        }
        boxes[(size_t)m * TOPK + i] = b;
    }
}

// ---------------- K4: 2048x2048 suppression bitmask, TRANSPOSED (iou > 0.45) ----------------
__global__ __launch_bounds__(1024) void k4_masks(const float4* __restrict__ boxes,
                                                 u64* __restrict__ maskT) {
    __shared__ float4 bx[TOPK];
    int m   = blockIdx.y;
    int grp = blockIdx.x;                       // 64 groups of 32 rows
    for (int i = threadIdx.x; i < TOPK; i += 1024)
        bx[i] = boxes[(size_t)m * TOPK + i];
    __syncthreads();

    int il = threadIdx.x & 31;
    int w  = threadIdx.x >> 5;
    int i  = grp * 32 + il;
    float4 b1 = bx[i];
    float a1 = __fmul_rn(__fsub_rn(b1.z, b1.x), __fsub_rn(b1.w, b1.y));
    u64 bits = 0ull;
    #pragma unroll 4
    for (int jj = 0; jj < 64; ++jj) {
        float4 b2 = bx[w * 64 + jj];
        float a2 = __fmul_rn(__fsub_rn(b2.z, b2.x), __fsub_rn(b2.w, b2.y));
        float iw = fmaxf(__fsub_rn(fminf(b1.z, b2.z), fmaxf(b1.x, b2.x)), 0.f);
        float ih = fmaxf(__fsub_rn(fminf(b1.w, b2.w), fmaxf(b1.y, b2.y)), 0.f);
        float inter = __fmul_rn(iw, ih);
        float uni   = __fsub_rn(__fadd_rn(a1, a2), inter);   // (a1+a2)-inter, ref order
        float iou   = __fdiv_rn(inter, uni);
        if (iou > 0.45f) bits |= (1ull << jj);
    }
    maskT[((size_t)m * 32 + w) * 2048 + i] = bits;
}

// ---------------- K5: greedy scan — BATCHED-ROUND MIS scan + FUSED output write ----------------
// IoU symmetry => dval(lane j) = set of rows conflicting with row j. Greedy NMS
// = lexicographically-first maximal independent set, computed in parallel rounds:
//   c_j = dval_j & alive & low(j); ready = ballot(alive_j && c_j==0);
//   removed = ballot(dval_j & ready); alive &= ~(ready | removed)
// Each round keeps ALL locally-first rows at once (~2-4 rounds/block vs ~40
// serial iterations). Provably identical kept-set to the sequential scan.
// Cross-block: waves 1..15 lagged-apply kb[blk-1] to remv words (unchanged R9/R13).
__global__ __launch_bounds__(1024) void k5_nms(const u64* __restrict__ sel,
                                               const u64* __restrict__ maskT,
                                               const float* __restrict__ pred,
                                               float4* __restrict__ out) {
    __shared__ u64 remv[32];
    __shared__ u64 kbshare[2];
    __shared__ u64 kws[32];
    int m = blockIdx.x;
    int t = threadIdx.x;
    int lane = t & 63;
    int wv = t >> 6;                            // wave id 0..15
    const u64* mt = maskT + (size_t)m * 32 * 2048;
    if (t < 32) remv[t] = 0ull;
    u64 dval = 0ull, sval = 0ull, tval = 0ull;
    u64 cfmask = 0ull;                          // C(blk-1 -> blk) suppression mask (uniform)
    u64 mybit = 1ull << lane;
    u64 lowmask = mybit - 1ull;                 // rows strictly below lane
    if (wv == 0) {
        dval = mt[(size_t)0 * 2048 + lane];
        sval = sel[(size_t)m * TOPK + lane];
        tval = mt[(size_t)0 * 2048 + 64 + lane];
    }
    __syncthreads();
    for (int blk = 0; blk < 32; ++blk) {
        if (wv == 0) {
            u64 dn = 0ull, sn = 0ull, tn = 0ull;
            if (blk < 31) {
                int r = (blk + 1) * 64 + lane;
                dn = mt[(size_t)(blk + 1) * 2048 + r];
                sn = sel[(size_t)m * TOPK + r];
                if (blk < 30) tn = mt[(size_t)(blk + 1) * 2048 + r + 64];
            }
            // ---- batched-round scan of block blk ----
            u64 ext = remv[blk];
            u64 validw = __ballot(sval != 0ull);
            u64 alive = validw & ~ext & ~cfmask;
            u64 kb = 0ull;
            while (alive) {
                u64 c = dval & alive & lowmask;
                u64 ready = __ballot(((alive & mybit) != 0ull) && (c == 0ull));
                kb |= ready;
                u64 removed = __ballot((dval & ready) != 0ull);
                alive &= ~(ready | removed);
            }
            cfmask = (blk < 31) ? __ballot((tval & kb) != 0ull) : 0ull;
            if (lane == 0) {
                kbshare[blk & 1] = kb;
                kws[blk] = kb;
            }
            dval = dn; sval = sn; tval = tn;
        } else if (blk >= 1) {
            u64 kb = kbshare[(blk - 1) & 1];
            int w1 = blk + wv;
            int w2 = blk + 15 + wv;
            u64 v1 = (w1 < 32) ? mt[(size_t)(blk - 1) * 2048 + w1 * 64 + lane] : 0ull;
            u64 v2 = (w2 < 32) ? mt[(size_t)(blk - 1) * 2048 + w2 * 64 + lane] : 0ull;
            u64 c1 = __ballot((v1 & kb) != 0ull);
            u64 c2 = __ballot((v2 & kb) != 0ull);
            if (w1 < 32 && lane == 0) remv[w1] |= c1;
            if (w2 < 32 && lane == 0) remv[w2] |= c2;
        }
        __syncthreads();
    }
    // fused output write
    const u64* sl = sel + (size_t)m * TOPK;
    float4* om = out + (size_t)m * TOPK * 4;
    #pragma unroll
    for (int q = t; q < TOPK * 4; q += 1024) {
        int c4 = q & 3;
        int r  = q >> 2;
        float4 o = make_float4(0.f, 0.f, 0.f, 0.f);
        if ((kws[r >> 6] >> (r & 63)) & 1ull) {
            u64 key = sl[r];
            unsigned idx = 0xFFFFFFFFu - (unsigned)(key & 0xFFFFFFFFull);
            const float4* rv = reinterpret_cast<const float4*>(pred + ((size_t)m * NA + idx) * 16);
            float4 v = rv[c4];
            if (c4 == 0) {
                float hw = __fmul_rn(v.z, 0.5f), hh = __fmul_rn(v.w, 0.5f);
                o = make_float4(__fsub_rn(v.x, hw), __fsub_rn(v.y, hh),
                                __fadd_rn(v.x, hw), __fadd_rn(v.y, hh));
            } else if (c4 == 1) {
                o = make_float4(__uint_as_float((unsigned)(key >> 32)), v.y, v.z, v.w);
            } else if (c4 == 2) {
                o = v;
            } else {
                o = make_float4(v.x, v.y, v.z, 0.f);
            }
        }
        om[q] = o;
    }
}

// ---------------- launch ----------------
extern "C" void kernel_launch(void* const* d_in, const int* in_sizes, int n_in,
                              void* d_out, int out_size, void* d_ws, size_t ws_size,
                              hipStream_t stream) {
    (void)in_sizes; (void)n_in; (void)out_size; (void)ws_size;
    const float* pred = (const float*)d_in[0];
    char* ws = (char*)d_ws;
    // layout (bytes):
    unsigned* cand32   = (unsigned*)(ws + 0);          // 8*100800*4 = 3,225,600
    u64*      comp     = (u64*)     (ws + 3225600);    // 8*4096*8   =   262,144
    u64*      sel      = (u64*)     (ws + 3487744);    // 8*2048*8   =   131,072
    float4*   boxes    = (float4*)  (ws + 3618816);    // 8*2048*16  =   262,144
    u64*      maskT    = (u64*)     (ws + 3880960);    // 8*32*2048*8= 4,194,304
    int*      histb    = (int*)     (ws + 8077312);    // 8*99*64*4  =   202,752
    int*      pos      = (int*)     (ws + 8280064);    // 32
    int*      cut      = (int*)     (ws + 8280096);    // 32
    float4*   out      = (float4*)d_out;

    hipLaunchKernelGGL(k1_scan,    dim3(NBLK1, NIMG),            dim3(256),  0, stream, pred, cand32, histb);
    hipLaunchKernelGGL(k2a_cutoff, dim3(NIMG),                   dim3(64),   0, stream, histb, cut, pos);
    hipLaunchKernelGGL(k2b_compact,dim3(NBLK1, NIMG),            dim3(1024), 0, stream, cand32, cut, comp, pos);
    hipLaunchKernelGGL(k2c_rank,   dim3(NIMG),                   dim3(1024), 0, stream, comp, pos, pred, sel, boxes);
    hipLaunchKernelGGL(k4_masks,   dim3(64, NIMG),               dim3(1024), 0, stream, boxes, maskT);
    hipLaunchKernelGGL(k5_nms,     dim3(NIMG),                   dim3(1024), 0, stream, sel, maskT, pred, out);
}